// Round 1
// baseline (243.428 us; speedup 1.0000x reference)
//
#include <hip/hip_runtime.h>
#include <stdint.h>

#define Mdim 4096
#define Kdim 4096
#define Ndim 4096

typedef __attribute__((ext_vector_type(4))) int v4i;
typedef __attribute__((ext_vector_type(16))) int v16i;

__device__ __forceinline__ void gload_lds16(const void* g, void* l) {
  __builtin_amdgcn_global_load_lds(
      (__attribute__((address_space(1))) void*)(uintptr_t)g,
      (__attribute__((address_space(3))) void*)(uint32_t)(uintptr_t)l,
      16, 0, 0);
}

// ---- pack x (int32 [M][K] -> int8 [M][K]) + row sums -----------------------
// Fully coalesced: int4 loads at lane stride 16B, dword stores.
__global__ __launch_bounds__(256) void pack_x_kernel(const int* __restrict__ x,
                                                     char* __restrict__ x8,
                                                     int* __restrict__ rsx) {
  const int row = blockIdx.x;
  const int t = threadIdx.x;
  const int4* src = (const int4*)(x + (size_t)row * Kdim);
  int* dst = (int*)(x8 + (size_t)row * Kdim);
  int sum = 0;
#pragma unroll
  for (int i = 0; i < 4; ++i) {
    int4 v = src[t + 256 * i];
    sum += v.x + v.y + v.z + v.w;
    dst[t + 256 * i] =
        (v.x & 0xff) | ((v.y & 0xff) << 8) | ((v.z & 0xff) << 16) | (v.w << 24);
  }
#pragma unroll
  for (int o = 32; o > 0; o >>= 1) sum += __shfl_down(sum, o, 64);
  __shared__ int red[4];
  if ((t & 63) == 0) red[t >> 6] = sum;
  __syncthreads();
  if (t == 0) rsx[row] = red[0] + red[1] + red[2] + red[3];
}

// ---- pack + transpose y (int32 [K][N] -> int8 (y-128) [N][K]) + colsum -----
// 64x64 tile. Phase 1: int4 coalesced loads, word-packed into LDS [k][nq]
// stride 17 (<=3-way banks). Phase 2: byte-gather (broadcast-heavy reads),
// int4 coalesced stores, colsum fused via quad shfl_xor + 1 atomic per n.
__global__ __launch_bounds__(256) void pack_yt_kernel(const int* __restrict__ y,
                                                      char* __restrict__ yt,
                                                      int* __restrict__ csy) {
  __shared__ int wt[64 * 17];
  const int t = threadIdx.x;
  const int n0 = blockIdx.x * 64;
  const int k0 = blockIdx.y * 64;
  const int c = t & 15;   // n-quad
  const int r0 = t >> 4;  // 0..15
#pragma unroll
  for (int s = 0; s < 4; ++s) {
    const int r = r0 + s * 16;  // k row 0..63
    int4 v = *(const int4*)(y + (size_t)(k0 + r) * Ndim + n0 + c * 4);
    v.x -= 128; v.y -= 128; v.z -= 128; v.w -= 128;
    wt[r * 17 + c] =
        (v.x & 0xff) | ((v.y & 0xff) << 8) | ((v.z & 0xff) << 16) | (v.w << 24);
  }
  __syncthreads();
  const int n = t >> 2;        // 0..63
  const int kq = t & 3;        // 16-k chunk
  const int colw = n >> 2;     // LDS word column
  const int byi = (n & 3) * 8; // byte select
  int outw[4];
  int bsum = 0;
#pragma unroll
  for (int j = 0; j < 4; ++j) {
    int b[4];
#pragma unroll
    for (int jj = 0; jj < 4; ++jj) {
      const int word = wt[(kq * 16 + j * 4 + jj) * 17 + colw];
      b[jj] = (word >> byi) & 0xff;
      bsum += (int)(char)b[jj];
    }
    outw[j] = b[0] | (b[1] << 8) | (b[2] << 16) | (b[3] << 24);
  }
  *(int4*)(yt + (size_t)(n0 + n) * Kdim + k0 + kq * 16) =
      make_int4(outw[0], outw[1], outw[2], outw[3]);
  bsum += __shfl_xor(bsum, 1, 64);
  bsum += __shfl_xor(bsum, 2, 64);
  if (kq == 0) atomicAdd(csy + n0 + n, bsum);
}

// ---- i8 GEMM: C = 7.5e-4*(A8 @ B8^T - 32*rsx[m] + 66*csy[n] - 2112*K) ------
// 512 thr / 8 waves, tile 256x256, BK=64, 1 block/CU (VGPR-limited anyway).
// T3+T4 counted-vmcnt pipeline: THREE LDS buffers (96 KB), prefetch depth 2,
// raw s_barrier + explicit s_waitcnt vmcnt(8) so each tile's 4 staging loads
// get ~2 COMPUTE periods (~600+ cy) to land instead of 1 (~256 cy). The old
// __syncthreads drained vmcnt to 0 each half-step -> 35% MfmaUtil ceiling.
// T5: setprio(1) around the MFMA cluster (waves now have role diversity).
__global__ __launch_bounds__(512, 2) void gemm_i8_kernel(
    const char* __restrict__ A, const char* __restrict__ B,
    const int* __restrict__ rsx, const int* __restrict__ csy,
    float* __restrict__ out) {
  __shared__ __align__(16) char lds[3 * 32768];  // buf: [As 16K | Bs 16K] x3
  const int t = threadIdx.x;
  const int l = t & 63;
  const int w = t >> 6;      // 0..7
  const int warow = w >> 1;  // 0..3 (x64 rows)
  const int wbcol = w & 1;   // 0..1 (x128 cols)
  const int bm = blockIdx.y * 256;
  const int bn = blockIdx.x * 256;

  v16i acc[2][4];
#pragma unroll
  for (int i = 0; i < 2; ++i)
#pragma unroll
    for (int j = 0; j < 4; ++j)
#pragma unroll
      for (int q = 0; q < 16; ++q) acc[i][j][q] = 0;

  // Staging: thread t -> LDS row srow (+128), 16B slot (t&3); slot holds
  // global chunk (t&3)^((row>>1)&3); key (t>>3)&3 invariant under +128.
  const int srow = t >> 2;  // 0..127
  const int cswz = ((t & 3) ^ ((t >> 3) & 3)) * 16;
  const char* gA = A + (size_t)(bm + srow) * Kdim + cswz;
  const char* gB = B + (size_t)(bn + srow) * Kdim + cswz;

#define STAGE(buf_off, koff)                                                  \
  do {                                                                        \
    _Pragma("unroll") for (int i = 0; i < 2; ++i)                             \
        gload_lds16(gA + (koff) + (size_t)i * 128 * Kdim,                     \
                    lds + (buf_off) + i * 8192 + t * 16);                     \
    _Pragma("unroll") for (int i = 0; i < 2; ++i)                             \
        gload_lds16(gB + (koff) + (size_t)i * 128 * Kdim,                     \
                    lds + (buf_off) + 16384 + i * 8192 + t * 16);             \
  } while (0)

  const int arow = warow * 64 + (l & 31);
  const int brow = wbcol * 128 + (l & 31);
  const int lhalf = l >> 5;
  const int lkey = (l >> 1) & 3;  // == (frag_row>>1)&3 for all frag rows

#define COMPUTE(buf_off)                                                      \
  do {                                                                        \
    const char* As = lds + (buf_off);                                         \
    const char* Bs = lds + (buf_off) + 16384;                                 \
    __builtin_amdgcn_s_setprio(1);                                            \
    _Pragma("unroll") for (int ks = 0; ks < 2; ++ks) {                        \
      const int slot = ((ks * 2 + lhalf) ^ lkey) * 16;                        \
      v4i a[2], b[4];                                                         \
      _Pragma("unroll") for (int i = 0; i < 2; ++i)                           \
          a[i] = *(const v4i*)(As + (arow + i * 32) * 64 + slot);             \
      _Pragma("unroll") for (int j = 0; j < 4; ++j)                           \
          b[j] = *(const v4i*)(Bs + (brow + j * 32) * 64 + slot);             \
      _Pragma("unroll") for (int i = 0; i < 2; ++i)                           \
          _Pragma("unroll") for (int j = 0; j < 4; ++j)                       \
              acc[i][j] = __builtin_amdgcn_mfma_i32_32x32x32_i8(              \
                  a[i], b[j], acc[i][j], 0, 0, 0);                            \
    }                                                                         \
    __builtin_amdgcn_s_setprio(0);                                            \
  } while (0)

// Raw barrier with compiler memory fences on both sides: the intrinsic alone
// is not an LLVM memory fence, so LDS reads/writes could otherwise migrate
// across it (learn_hip rule #18 family).
#define BAR()                                                                 \
  do {                                                                        \
    asm volatile("" ::: "memory");                                            \
    __builtin_amdgcn_s_barrier();                                             \
    asm volatile("" ::: "memory");                                            \
  } while (0)
#define WAITV(n) asm volatile("s_waitcnt vmcnt(" #n ")" ::: "memory")

  // Prologue: fill all three buffers (12 loads/wave in flight), wait only the
  // oldest tile (vmcnt(8) leaves tiles 1,2 flying), then sync.
  STAGE(0, 0);
  STAGE(32768, 1 * 64);
  STAGE(65536, 2 * 64);
  WAITV(8);
  BAR();

  // Steady state per tile kt (buffer kt%3):
  //   COMPUTE(cur)                 reads buf[cur]; tiles kt+1,kt+2 in flight
  //   BAR                          all waves done reading buf[cur]
  //   STAGE(cur, kt+3)             overwrite now safe; 12 loads in flight
  //   WAITV(8)                     tile kt+1 landed (8 newer still flying)
  //   BAR                          every wave's kt+1 loads landed
  // Tiles 0..59 in a x3-unrolled loop (constant buffer offsets), then peel.
#pragma unroll 1
  for (int kt = 0; kt < 60; kt += 3) {
    COMPUTE(0);
    BAR();
    STAGE(0, (kt + 3) * 64);
    WAITV(8);
    BAR();
    COMPUTE(32768);
    BAR();
    STAGE(32768, (kt + 4) * 64);
    WAITV(8);
    BAR();
    COMPUTE(65536);
    BAR();
    STAGE(65536, (kt + 5) * 64);
    WAITV(8);
    BAR();
  }
  // kt = 60: stage last tile (63 -> buf 0), in flight 61,62,63 -> wait 61
  COMPUTE(0);
  BAR();
  STAGE(0, 63 * 64);
  WAITV(8);
  BAR();
  // kt = 61: in flight 62,63 -> wait 62
  COMPUTE(32768);
  BAR();
  WAITV(4);
  BAR();
  // kt = 62: in flight 63 -> wait 63
  COMPUTE(65536);
  BAR();
  WAITV(0);
  BAR();
  // kt = 63
  COMPUTE(0);

  // Epilogue. C/D 32x32 layout: col=lane&31, row=(r&3)+8*(r>>2)+4*(lane>>5)
  const int col = l & 31;
#pragma unroll
  for (int i = 0; i < 2; ++i) {
    const int gm0 = bm + warow * 64 + i * 32;
#pragma unroll
    for (int j = 0; j < 4; ++j) {
      const int gn = bn + wbcol * 128 + j * 32 + col;
      const int cs = 66 * csy[gn] - 8650752;  // -2112*4096
#pragma unroll
      for (int r = 0; r < 16; ++r) {
        const int row = (r & 3) + 8 * (r >> 2) + 4 * lhalf;
        const int gm = gm0 + row;
        const int val = acc[i][j][r] - 32 * rsx[gm] + cs;
        out[(size_t)gm * Ndim + gn] = 7.5e-4f * (float)val;
      }
    }
  }
#undef STAGE
#undef COMPUTE
#undef BAR
#undef WAITV
}

extern "C" void kernel_launch(void* const* d_in, const int* in_sizes, int n_in,
                              void* d_out, int out_size, void* d_ws, size_t ws_size,
                              hipStream_t stream) {
  (void)in_sizes; (void)n_in; (void)out_size; (void)ws_size;
  const int* x = (const int*)d_in[0];
  const int* y = (const int*)d_in[1];
  float* out = (float*)d_out;
  char* ws = (char*)d_ws;
  char* x8 = ws;                                          // 16 MB
  char* yt = ws + (size_t)Mdim * Kdim;                    // 16 MB
  int* rsx = (int*)(ws + (size_t)Mdim * Kdim + (size_t)Kdim * Ndim);
  int* csy = rsx + Mdim;

  hipMemsetAsync(csy, 0, Ndim * sizeof(int), stream);
  pack_x_kernel<<<Mdim, 256, 0, stream>>>(x, x8, rsx);
  pack_yt_kernel<<<dim3(Ndim / 64, Kdim / 64), 256, 0, stream>>>(y, yt, csy);
  gemm_i8_kernel<<<dim3(Ndim / 256, Mdim / 256), 512, 0, stream>>>(x8, yt, rsx, csy, out);
}

// Round 2
// 238.910 us; speedup vs baseline: 1.0189x; 1.0189x over previous
//
#include <hip/hip_runtime.h>
#include <stdint.h>

#define Mdim 4096
#define Kdim 4096
#define Ndim 4096

typedef __attribute__((ext_vector_type(4))) int v4i;
typedef __attribute__((ext_vector_type(16))) int v16i;

__device__ __forceinline__ void gload_lds16(const void* g, void* l) {
  __builtin_amdgcn_global_load_lds(
      (__attribute__((address_space(1))) void*)(uintptr_t)g,
      (__attribute__((address_space(3))) void*)(uint32_t)(uintptr_t)l,
      16, 0, 0);
}

// ---- pack x (int32 [M][K] -> int8 [M][K]) + row sums -----------------------
__global__ __launch_bounds__(256) void pack_x_kernel(const int* __restrict__ x,
                                                     char* __restrict__ x8,
                                                     int* __restrict__ rsx) {
  const int row = blockIdx.x;
  const int t = threadIdx.x;
  const int4* src = (const int4*)(x + (size_t)row * Kdim);
  int* dst = (int*)(x8 + (size_t)row * Kdim);
  int sum = 0;
#pragma unroll
  for (int i = 0; i < 4; ++i) {
    int4 v = src[t + 256 * i];
    sum += v.x + v.y + v.z + v.w;
    dst[t + 256 * i] =
        (v.x & 0xff) | ((v.y & 0xff) << 8) | ((v.z & 0xff) << 16) | (v.w << 24);
  }
#pragma unroll
  for (int o = 32; o > 0; o >>= 1) sum += __shfl_down(sum, o, 64);
  __shared__ int red[4];
  if ((t & 63) == 0) red[t >> 6] = sum;
  __syncthreads();
  if (t == 0) rsx[row] = red[0] + red[1] + red[2] + red[3];
}

// ---- pack + transpose y (int32 [K][N] -> int8 (y-128) [N][K]) + colsum -----
__global__ __launch_bounds__(256) void pack_yt_kernel(const int* __restrict__ y,
                                                      char* __restrict__ yt,
                                                      int* __restrict__ csy) {
  __shared__ int wt[64 * 17];
  const int t = threadIdx.x;
  const int n0 = blockIdx.x * 64;
  const int k0 = blockIdx.y * 64;
  const int c = t & 15;   // n-quad
  const int r0 = t >> 4;  // 0..15
#pragma unroll
  for (int s = 0; s < 4; ++s) {
    const int r = r0 + s * 16;  // k row 0..63
    int4 v = *(const int4*)(y + (size_t)(k0 + r) * Ndim + n0 + c * 4);
    v.x -= 128; v.y -= 128; v.z -= 128; v.w -= 128;
    wt[r * 17 + c] =
        (v.x & 0xff) | ((v.y & 0xff) << 8) | ((v.z & 0xff) << 16) | (v.w << 24);
  }
  __syncthreads();
  const int n = t >> 2;        // 0..63
  const int kq = t & 3;        // 16-k chunk
  const int colw = n >> 2;     // LDS word column
  const int byi = (n & 3) * 8; // byte select
  int outw[4];
  int bsum = 0;
#pragma unroll
  for (int j = 0; j < 4; ++j) {
    int b[4];
#pragma unroll
    for (int jj = 0; jj < 4; ++jj) {
      const int word = wt[(kq * 16 + j * 4 + jj) * 17 + colw];
      b[jj] = (word >> byi) & 0xff;
      bsum += (int)(char)b[jj];
    }
    outw[j] = b[0] | (b[1] << 8) | (b[2] << 16) | (b[3] << 24);
  }
  *(int4*)(yt + (size_t)(n0 + n) * Kdim + k0 + kq * 16) =
      make_int4(outw[0], outw[1], outw[2], outw[3]);
  bsum += __shfl_xor(bsum, 1, 64);
  bsum += __shfl_xor(bsum, 2, 64);
  if (kq == 0) atomicAdd(csy + n0 + n, bsum);
}

// ---- i8 GEMM: C = 7.5e-4*(A8 @ B8^T - 32*rsx[m] + 66*csy[n] - 2112*K) ------
// 512 thr / 8 waves, tile 256x256, BK=64, 1 block/CU.
// T3+T4+T5 8-phase-style schedule (m201 template, regime-gated combo):
// each K-tile = 4 phases of {ds_read frags, 1 staging load, s_barrier,
// sched_barrier(0), setprio(1), 4x MFMA, setprio(0), sched_barrier(0),
// s_barrier}. The wave ISSUES its MFMA cluster and reaches the barrier while
// the matrix pipe drains (~290 cy/SIMD); the next phase's ds_reads + staging
// issue under that drain -> LDS and MFMA cross-cover instead of serializing.
// 3 LDS buffers, prefetch depth 2; tile-boundary s_waitcnt vmcnt(4) only
// (never 0 in steady state) -> each tile's 4 loads get a full tile (~1200cy)
// to land.
__global__ __launch_bounds__(512, 2) void gemm_i8_kernel(
    const char* __restrict__ A, const char* __restrict__ B,
    const int* __restrict__ rsx, const int* __restrict__ csy,
    float* __restrict__ out) {
  __shared__ __align__(16) char lds[3 * 32768];  // buf: [As 16K | Bs 16K] x3
  const int t = threadIdx.x;
  const int l = t & 63;
  const int w = t >> 6;      // 0..7
  const int warow = w >> 1;  // 0..3 (x64 rows)
  const int wbcol = w & 1;   // 0..1 (x128 cols)
  const int bm = blockIdx.y * 256;
  const int bn = blockIdx.x * 256;

  v16i acc[2][4];
#pragma unroll
  for (int i = 0; i < 2; ++i)
#pragma unroll
    for (int j = 0; j < 4; ++j)
#pragma unroll
      for (int q = 0; q < 16; ++q) acc[i][j][q] = 0;

  // Staging: thread t -> LDS row srow (+128), 16B slot (t&3); slot holds
  // global chunk (t&3)^((row>>1)&3); key (t>>3)&3 invariant under +128.
  const int srow = t >> 2;  // 0..127
  const int cswz = ((t & 3) ^ ((t >> 3) & 3)) * 16;
  const char* gA = A + (size_t)(bm + srow) * Kdim + cswz;
  const char* gB = B + (size_t)(bn + srow) * Kdim + cswz;

// Full-tile stage (prologue only).
#define STAGE(buf_off, koff)                                                  \
  do {                                                                        \
    _Pragma("unroll") for (int i = 0; i < 2; ++i)                             \
        gload_lds16(gA + (koff) + (size_t)i * 128 * Kdim,                     \
                    lds + (buf_off) + i * 8192 + t * 16);                     \
    _Pragma("unroll") for (int i = 0; i < 2; ++i)                             \
        gload_lds16(gB + (koff) + (size_t)i * 128 * Kdim,                     \
                    lds + (buf_off) + 16384 + i * 8192 + t * 16);             \
  } while (0)

// One staging load (1 of 4 per tile), idx 0..3: {A0, A1, B0, B1}.
#define STG(sbo, koff, idx)                                                   \
  gload_lds16(((idx) < 2 ? gA : gB) + (koff) + (size_t)((idx)&1) * 128 * Kdim,\
              lds + (sbo) + ((idx) < 2 ? 0 : 16384) + ((idx)&1) * 8192 +      \
                  t * 16)

  const int arow = warow * 64 + (l & 31);
  const int brow = wbcol * 128 + (l & 31);
  const int lhalf = l >> 5;
  const int lkey = (l >> 1) & 3;  // == (frag_row>>1)&3 for all frag rows
  const int slot0 = ((0 + lhalf) ^ lkey) * 16;  // ks=0 16B slot
  const int slot1 = ((2 + lhalf) ^ lkey) * 16;  // ks=1 16B slot

#define MFMA(a, b, c) __builtin_amdgcn_mfma_i32_32x32x32_i8(a, b, c, 0, 0, 0)
#define SETP(n) __builtin_amdgcn_s_setprio(n)
#define FENCE() __builtin_amdgcn_sched_barrier(0)
// Raw barrier with compiler memory fences (the intrinsic alone is not an
// LLVM memory fence); FENCE() separately pins non-memory ops (MFMA).
#define BAR()                                                                 \
  do {                                                                        \
    asm volatile("" ::: "memory");                                            \
    __builtin_amdgcn_s_barrier();                                             \
    asm volatile("" ::: "memory");                                            \
  } while (0)
#define WAITV(n) asm volatile("s_waitcnt vmcnt(" #n ")" ::: "memory")

// One K-tile = 4 phases. a0,a1 stay live ph0->ph1 and ph2->ph3.
// TAILWAIT sits at the tile boundary (before the last barrier): in steady
// state WAITV(4) = "everything except the 4 loads issued THIS tile is done"
// => next tile's buffer landed in every wave, certified by the barrier.
#define TILE(bo, sbo, skoff, dostage, TAILWAIT)                               \
  do {                                                                        \
    const char* As = lds + (bo);                                              \
    const char* Bs = lds + (bo) + 16384;                                      \
    v4i a0, a1, b0, b1;                                                       \
    /* phase 0: ks=0, frags a0,a1,b0,b1 -> acc[*][0..1] */                    \
    a0 = *(const v4i*)(As + arow * 64 + slot0);                               \
    a1 = *(const v4i*)(As + (arow + 32) * 64 + slot0);                        \
    b0 = *(const v4i*)(Bs + brow * 64 + slot0);                               \
    b1 = *(const v4i*)(Bs + (brow + 32) * 64 + slot0);                        \
    if (dostage) STG(sbo, skoff, 0);                                          \
    BAR();                                                                    \
    FENCE();                                                                  \
    SETP(1);                                                                  \
    acc[0][0] = MFMA(a0, b0, acc[0][0]);                                      \
    acc[0][1] = MFMA(a0, b1, acc[0][1]);                                      \
    acc[1][0] = MFMA(a1, b0, acc[1][0]);                                      \
    acc[1][1] = MFMA(a1, b1, acc[1][1]);                                      \
    SETP(0);                                                                  \
    FENCE();                                                                  \
    BAR();                                                                    \
    /* phase 1: ks=0, frags b2,b3 -> acc[*][2..3] */                          \
    {                                                                         \
      v4i b2 = *(const v4i*)(Bs + (brow + 64) * 64 + slot0);                  \
      v4i b3 = *(const v4i*)(Bs + (brow + 96) * 64 + slot0);                  \
      if (dostage) STG(sbo, skoff, 1);                                        \
      BAR();                                                                  \
      FENCE();                                                                \
      SETP(1);                                                                \
      acc[0][2] = MFMA(a0, b2, acc[0][2]);                                    \
      acc[0][3] = MFMA(a0, b3, acc[0][3]);                                    \
      acc[1][2] = MFMA(a1, b2, acc[1][2]);                                    \
      acc[1][3] = MFMA(a1, b3, acc[1][3]);                                    \
      SETP(0);                                                                \
      FENCE();                                                                \
      BAR();                                                                  \
    }                                                                         \
    /* phase 2: ks=1, frags a0,a1,b0,b1 */                                    \
    a0 = *(const v4i*)(As + arow * 64 + slot1);                               \
    a1 = *(const v4i*)(As + (arow + 32) * 64 + slot1);                        \
    b0 = *(const v4i*)(Bs + brow * 64 + slot1);                               \
    b1 = *(const v4i*)(Bs + (brow + 32) * 64 + slot1);                        \
    if (dostage) STG(sbo, skoff, 2);                                          \
    BAR();                                                                    \
    FENCE();                                                                  \
    SETP(1);                                                                  \
    acc[0][0] = MFMA(a0, b0, acc[0][0]);                                      \
    acc[0][1] = MFMA(a0, b1, acc[0][1]);                                      \
    acc[1][0] = MFMA(a1, b0, acc[1][0]);                                      \
    acc[1][1] = MFMA(a1, b1, acc[1][1]);                                      \
    SETP(0);                                                                  \
    FENCE();                                                                  \
    BAR();                                                                    \
    /* phase 3: ks=1, frags b2,b3 + tile-boundary vmcnt wait */               \
    {                                                                         \
      v4i b2 = *(const v4i*)(Bs + (brow + 64) * 64 + slot1);                  \
      v4i b3 = *(const v4i*)(Bs + (brow + 96) * 64 + slot1);                  \
      if (dostage) STG(sbo, skoff, 3);                                        \
      BAR();                                                                  \
      FENCE();                                                                \
      SETP(1);                                                                \
      acc[0][2] = MFMA(a0, b2, acc[0][2]);                                    \
      acc[0][3] = MFMA(a0, b3, acc[0][3]);                                    \
      acc[1][2] = MFMA(a1, b2, acc[1][2]);                                    \
      acc[1][3] = MFMA(a1, b3, acc[1][3]);                                    \
      SETP(0);                                                                \
      FENCE();                                                                \
      TAILWAIT;                                                               \
      BAR();                                                                  \
    }                                                                         \
  } while (0)

  // Prologue: stage tiles 0 and 1, wait tile 0 only (tile 1 stays in flight).
  STAGE(0, 0);
  STAGE(32768, 64);
  WAITV(4);
  BAR();

  // Steady state: during tile kt (buf kt%3) stage tile kt+2 (buf (kt+2)%3,
  // whose readers finished at the kt-start barrier), 1 load per phase.
#pragma unroll 1
  for (int kt = 0; kt < 60; kt += 3) {
    TILE(0, 65536, (kt + 2) * 64, 1, WAITV(4));
    TILE(32768, 0, (kt + 3) * 64, 1, WAITV(4));
    TILE(65536, 32768, (kt + 4) * 64, 1, WAITV(4));
  }
  TILE(0, 65536, 62 * 64, 1, WAITV(4));  // kt=60, stages t62
  TILE(32768, 0, 63 * 64, 1, WAITV(4));  // kt=61, stages t63
  TILE(65536, 0, 0, 0, WAITV(0));        // kt=62, drain t63
  TILE(0, 0, 0, 0, (void)0);             // kt=63

  // Epilogue. C/D 32x32 layout: col=lane&31, row=(r&3)+8*(r>>2)+4*(lane>>5)
  const int col = l & 31;
#pragma unroll
  for (int i = 0; i < 2; ++i) {
    const int gm0 = bm + warow * 64 + i * 32;
#pragma unroll
    for (int j = 0; j < 4; ++j) {
      const int gn = bn + wbcol * 128 + j * 32 + col;
      const int cs = 66 * csy[gn] - 8650752;  // -2112*4096
#pragma unroll
      for (int r = 0; r < 16; ++r) {
        const int row = (r & 3) + 8 * (r >> 2) + 4 * lhalf;
        const int gm = gm0 + row;
        const int val = acc[i][j][r] - 32 * rsx[gm] + cs;
        out[(size_t)gm * Ndim + gn] = 7.5e-4f * (float)val;
      }
    }
  }
#undef STAGE
#undef STG
#undef TILE
#undef MFMA
#undef SETP
#undef FENCE
#undef BAR
#undef WAITV
}

extern "C" void kernel_launch(void* const* d_in, const int* in_sizes, int n_in,
                              void* d_out, int out_size, void* d_ws, size_t ws_size,
                              hipStream_t stream) {
  (void)in_sizes; (void)n_in; (void)out_size; (void)ws_size;
  const int* x = (const int*)d_in[0];
  const int* y = (const int*)d_in[1];
  float* out = (float*)d_out;
  char* ws = (char*)d_ws;
  char* x8 = ws;                                          // 16 MB
  char* yt = ws + (size_t)Mdim * Kdim;                    // 16 MB
  int* rsx = (int*)(ws + (size_t)Mdim * Kdim + (size_t)Kdim * Ndim);
  int* csy = rsx + Mdim;

  hipMemsetAsync(csy, 0, Ndim * sizeof(int), stream);
  pack_x_kernel<<<Mdim, 256, 0, stream>>>(x, x8, rsx);
  pack_yt_kernel<<<dim3(Ndim / 64, Kdim / 64), 256, 0, stream>>>(y, yt, csy);
  gemm_i8_kernel<<<dim3(Ndim / 256, Mdim / 256), 512, 0, stream>>>(x8, yt, rsx, csy, out);
}